// Round 20
// baseline (312.469 us; speedup 1.0000x reference)
//
#include <hip/hip_runtime.h>
#include <hip/hip_bf16.h>

#define NN 2048
#define QQ 9
#define DD 256
#define LL 4
#define BB 32
#define EE 32768
#define EPSV 1e-5f

typedef __attribute__((ext_vector_type(8))) short bf16x8;
typedef __attribute__((ext_vector_type(8))) ushort u16x8;
typedef __attribute__((ext_vector_type(4))) float f32x4;
typedef __attribute__((ext_vector_type(2))) float f32x2;
typedef __attribute__((ext_vector_type(4))) int i32x4;

__device__ __forceinline__ ushort f2bf(float x)
{
    uint u = __float_as_uint(x);
    u += 0x7FFFu + ((u >> 16) & 1u);
    return (ushort)(u >> 16);
}
__device__ __forceinline__ float bf2f(ushort h)
{
    return __uint_as_float(((uint)h) << 16);
}

// decode one u32 (2 packed bf16) and accumulate into a float2 (pk_add-friendly)
__device__ __forceinline__ void addw(uint wd, f32x2& a)
{
    f32x2 v;
    v.x = __uint_as_float(wd << 16);
    v.y = __uint_as_float(wd & 0xffff0000u);
    a += v;
}

// async global -> LDS, 16 bytes per lane; lptr wave-uniform (HW adds lane*16)
__device__ __forceinline__ void gload16(const ushort* g, ushort* l)
{
    __builtin_amdgcn_global_load_lds(
        (const __attribute__((address_space(1))) void*)g,
        (__attribute__((address_space(3))) void*)l, 16, 0, 0);
}

// ---------- CSR build ----------
__global__ void k_count(const int* __restrict__ src, int* __restrict__ cnt)
{
    int e = blockIdx.x * blockDim.x + threadIdx.x;
    if (e < EE) atomicAdd(&cnt[src[e]], 1);
}

__global__ __launch_bounds__(256) void k_scan(const int* __restrict__ cnt,
                                              int* __restrict__ row_ptr,
                                              int* __restrict__ cursor)
{
    __shared__ int part[256];
    int t = threadIdx.x;
    int local[8];
    int s = 0;
    #pragma unroll
    for (int i = 0; i < 8; ++i) { local[i] = cnt[t * 8 + i]; s += local[i]; }
    part[t] = s;
    __syncthreads();
    for (int off = 1; off < 256; off <<= 1) {
        int v = (t >= off) ? part[t - off] : 0;
        __syncthreads();
        part[t] += v;
        __syncthreads();
    }
    int run = part[t] - s;
    #pragma unroll
    for (int i = 0; i < 8; ++i) {
        int idx = t * 8 + i;
        row_ptr[idx] = run;
        cursor[idx]  = run;
        run += local[i];
    }
    if (t == 255) row_ptr[NN] = run;
}

__global__ void k_fill(const int* __restrict__ src, const int* __restrict__ dst,
                       int* __restrict__ cursor, int* __restrict__ col)
{
    int e = blockIdx.x * blockDim.x + threadIdx.x;
    if (e < EE) {
        int p = atomicAdd(&cursor[src[e]], 1);
        col[p] = dst[e];
    }
}

// ---------- h0 = bf16(batch with rows [0,Q) <- emotion_emb) ----------
__global__ void k_prep0(const float4* __restrict__ bf, const float4* __restrict__ emo,
                        ushort4* __restrict__ hhi)
{
    int total = BB * NN * (DD / 4);
    for (int idx = blockIdx.x * blockDim.x + threadIdx.x; idx < total;
         idx += gridDim.x * blockDim.x) {
        int d4 = idx & 63;
        int n  = (idx >> 6) & (NN - 1);
        float4 v = (n < QQ) ? emo[n * 64 + d4] : bf[idx];
        ushort4 h;
        h.x = f2bf(v.x); h.y = f2bf(v.y); h.z = f2bf(v.z); h.w = f2bf(v.w);
        hhi[idx] = h;
    }
}

// ---------- pooled = h + A.h : batch-paired gather, word-decode + pk adds ----------
__global__ __launch_bounds__(256) void k_spmm6(
    const ushort* __restrict__ phi,
    const int* __restrict__ row_ptr, const int* __restrict__ col,
    ushort* __restrict__ ohi)
{
    int x     = blockIdx.x & 7;          // XCD slice: batches [4x, 4x+4)
    int local = blockIdx.x >> 3;
    int w     = threadIdx.x >> 6;
    int t     = threadIdx.x & 63;
    int inst  = local * 4 + w;
    int pl    = inst >> 11;
    int n     = inst & (NN - 1);
    int b     = x * 4 + pl * 2 + (t >> 5);
    int q     = t & 31;
    const uint* base = (const uint*)(phi + (size_t)b * NN * DD) + q * 4;

    f32x2 a[4];
    {
        uint4 sv = *(const uint4*)(base + (size_t)n * 128);
        a[0] = (f32x2)0.f; a[1] = (f32x2)0.f; a[2] = (f32x2)0.f; a[3] = (f32x2)0.f;
        addw(sv.x, a[0]); addw(sv.y, a[1]); addw(sv.z, a[2]); addw(sv.w, a[3]);
    }

    int beg = row_ptr[n], end = row_ptr[n + 1];
    int j = beg;
    for (; j < end && (j & 3); ++j) {
        uint4 g = *(const uint4*)(base + (size_t)col[j] * 128);
        addw(g.x, a[0]); addw(g.y, a[1]); addw(g.z, a[2]); addw(g.w, a[3]);
    }
    for (; j + 8 <= end; j += 8) {
        i32x4 c0 = *(const i32x4*)(col + j);
        i32x4 c1 = *(const i32x4*)(col + j + 4);
        uint4 g[8];
        g[0] = *(const uint4*)(base + (size_t)c0.x * 128);
        g[1] = *(const uint4*)(base + (size_t)c0.y * 128);
        g[2] = *(const uint4*)(base + (size_t)c0.z * 128);
        g[3] = *(const uint4*)(base + (size_t)c0.w * 128);
        g[4] = *(const uint4*)(base + (size_t)c1.x * 128);
        g[5] = *(const uint4*)(base + (size_t)c1.y * 128);
        g[6] = *(const uint4*)(base + (size_t)c1.z * 128);
        g[7] = *(const uint4*)(base + (size_t)c1.w * 128);
        #pragma unroll
        for (int u = 0; u < 8; ++u) {
            addw(g[u].x, a[0]); addw(g[u].y, a[1]);
            addw(g[u].z, a[2]); addw(g[u].w, a[3]);
        }
    }
    if (j + 4 <= end) {
        i32x4 c = *(const i32x4*)(col + j);
        uint4 g[4];
        g[0] = *(const uint4*)(base + (size_t)c.x * 128);
        g[1] = *(const uint4*)(base + (size_t)c.y * 128);
        g[2] = *(const uint4*)(base + (size_t)c.z * 128);
        g[3] = *(const uint4*)(base + (size_t)c.w * 128);
        #pragma unroll
        for (int u = 0; u < 4; ++u) {
            addw(g[u].x, a[0]); addw(g[u].y, a[1]);
            addw(g[u].z, a[2]); addw(g[u].w, a[3]);
        }
        j += 4;
    }
    for (; j < end; ++j) {
        uint4 g = *(const uint4*)(base + (size_t)col[j] * 128);
        addw(g.x, a[0]); addw(g.y, a[1]); addw(g.z, a[2]); addw(g.w, a[3]);
    }

    u16x8 o;
    #pragma unroll
    for (int k = 0; k < 4; ++k) {
        o[2 * k]     = f2bf(a[k].x);
        o[2 * k + 1] = f2bf(a[k].y);
    }
    *(u16x8*)(ohi + ((size_t)b * NN + n) * DD + q * 8) = o;
}

// ---------- weight prep: Wt[mat][n][k] = bf16(W[mat][k][n]) ----------
__global__ __launch_bounds__(256) void k_wprep(const float* __restrict__ w1,
                                               const float* __restrict__ w2,
                                               ushort* __restrict__ wt_hi)
{
    __shared__ float tile[32][36];
    int bx = blockIdx.x;
    int mat = bx >> 6;
    int tt  = bx & 63;
    int tk = (tt >> 3) * 32;
    int tn = (tt & 7) * 32;
    const float* src = (mat < 4) ? (w1 + (size_t)mat * DD * DD)
                                 : (w2 + (size_t)(mat - 4) * DD * DD);
    int t = threadIdx.x;
    int r = t >> 3, c0 = (t & 7) * 4;
    float4 v = *(const float4*)(src + (size_t)(tk + r) * DD + tn + c0);
    tile[r][c0 + 0] = v.x; tile[r][c0 + 1] = v.y;
    tile[r][c0 + 2] = v.z; tile[r][c0 + 3] = v.w;
    __syncthreads();
    int nn = t >> 3, kq = (t & 7) * 4;
    ushort4 hh;
    hh.x = f2bf(tile[kq + 0][nn]); hh.y = f2bf(tile[kq + 1][nn]);
    hh.z = f2bf(tile[kq + 2][nn]); hh.w = f2bf(tile[kq + 3][nn]);
    size_t off = (size_t)mat * DD * DD + (size_t)(tn + nn) * DD + tk + kq;
    *(ushort4*)(wt_hi + off) = hh;
}

// ---------- fused layer GEMM + score, counted-vmcnt pipeline (T4) ----------
// 64 rows x 256 N, 4 waves (32m x 128n). AT (32KB) holds A, then t, then h
// (chunk-XOR swizzle phys = chunk ^ (row&7)). W triple-buffered (3x16KB),
// prefetched 2 K-steps ahead; barriers use s_waitcnt vmcnt(4) + raw s_barrier
// so 4 W-loads stay in flight across every barrier. LDS = exactly 80 KB.
__global__ __launch_bounds__(256) void k_gemm_fused(
    const ushort* __restrict__ A, const ushort* __restrict__ W1t,
    const ushort* __restrict__ W2t,
    const float* __restrict__ b1, const float* __restrict__ g1,
    const float* __restrict__ be1, const float* __restrict__ m1,
    const float* __restrict__ v1,
    const float* __restrict__ b2, const float* __restrict__ g2,
    const float* __restrict__ be2, const float* __restrict__ m2,
    const float* __restrict__ v2,
    const float* __restrict__ pw, const float* __restrict__ pb, int l,
    ushort* __restrict__ O, float* __restrict__ out)
{
    __shared__ alignas(16) ushort SM[40960];     // AT 16384 | Ws 3 x 8192 (80 KB)
    ushort* AT = SM;                             // 64 x 256, swizzled

    int tid = threadIdx.x;
    int x  = blockIdx.x & 7;
    int lm = blockIdx.x >> 3;
    int m0 = x * 8192 + lm * 64;
    int lane = tid & 63;
    int w = tid >> 6;
    int wm = w & 1, wn = w >> 1;                 // wave tile: 32m x 128n
    int lr = lane & 15, kg = lane >> 4;
    int rg = lane >> 4;
    int kgp = kg ^ ((lr >> 1) & 3);              // Ws read swizzle (R13)

    // W DMA source geometry (R13)
    int sc   = (lane & 3) ^ ((lane >> 3) & 3);
    int srow = lane >> 2;

    // ---- issue A tile DMA (8 instrs/wave, R15-proven swizzled pattern) ----
    #pragma unroll
    for (int i = 0; i < 8; ++i) {
        int row = (w * 8 + i) * 2 + (lane >> 5);
        int pc  = lane & 31;
        int lc  = pc ^ (row & 7);
        gload16(A + (size_t)(m0 + row) * DD + lc * 8, AT + (w * 8 + i) * 512);
    }
    // ---- issue W1 kc=0 -> buf0, kc=1 -> buf1 ----
    #pragma unroll
    for (int i = 0; i < 4; ++i) {
        int seg = i * 4 + w;
        gload16(W1t + (size_t)(seg * 16 + srow) * DD + sc * 8,
                SM + 16384 + seg * 512);
    }
    #pragma unroll
    for (int i = 0; i < 4; ++i) {
        int seg = i * 4 + w;
        gload16(W1t + (size_t)(seg * 16 + srow) * DD + 32 + sc * 8,
                SM + 16384 + 8192 + seg * 512);
    }

    f32x4 acc[2][8];
    #pragma unroll
    for (int m = 0; m < 2; ++m)
        #pragma unroll
        for (int n = 0; n < 8; ++n) acc[m][n] = (f32x4)0.f;

    // ---- phase 1 K-loop: counted waits, W prefetch 2 ahead ----
    #pragma unroll
    for (int kc = 0; kc < 8; ++kc) {
        if (kc < 7) asm volatile("s_waitcnt vmcnt(4)" ::: "memory");
        else        asm volatile("s_waitcnt vmcnt(0)" ::: "memory");
        __builtin_amdgcn_sched_barrier(0);
        __builtin_amdgcn_s_barrier();
        __builtin_amdgcn_sched_barrier(0);
        if (kc < 6) {
            int ko = (kc + 2) * 32;
            int bi = (kc + 2) % 3;
            #pragma unroll
            for (int i = 0; i < 4; ++i) {
                int seg = i * 4 + w;
                gload16(W1t + (size_t)(seg * 16 + srow) * DD + ko + sc * 8,
                        SM + 16384 + bi * 8192 + seg * 512);
            }
        }
        const ushort* Wb = SM + 16384 + (kc % 3) * 8192;
        bf16x8 ah[2], bh[8];
        #pragma unroll
        for (int mi = 0; mi < 2; ++mi) {
            int row = wm * 32 + mi * 16 + lr;
            ah[mi] = *(const bf16x8*)&AT[row * 256 + (((kc * 4 + kg) ^ (row & 7)) * 8)];
        }
        #pragma unroll
        for (int n = 0; n < 8; ++n)
            bh[n] = *(const bf16x8*)&Wb[(wn * 128 + n * 16 + lr) * 32 + kgp * 8];
        #pragma unroll
        for (int mi = 0; mi < 2; ++mi)
            #pragma unroll
            for (int n = 0; n < 8; ++n)
                acc[mi][n] = __builtin_amdgcn_mfma_f32_16x16x32_bf16(
                    ah[mi], bh[n], acc[mi][n], 0, 0, 0);
    }
    __builtin_amdgcn_s_barrier();                // all A reads done
    __builtin_amdgcn_sched_barrier(0);

    // ---- epi-1 params (older than W2 prefetch so compiler waits don't drain) ----
    float sN[8], svN[8];
    #pragma unroll
    for (int n = 0; n < 8; ++n) {
        int jj = wn * 128 + n * 16 + lr;
        sN[n]  = g1[jj] * rsqrtf(v1[jj] + EPSV);
        svN[n] = (b1[jj] - m1[jj]) * sN[n] + be1[jj];
    }
    // ---- issue W2 kc=0 -> buf0, kc=1 -> buf1 (land under epilogue 1) ----
    #pragma unroll
    for (int i = 0; i < 4; ++i) {
        int seg = i * 4 + w;
        gload16(W2t + (size_t)(seg * 16 + srow) * DD + sc * 8,
                SM + 16384 + seg * 512);
    }
    #pragma unroll
    for (int i = 0; i < 4; ++i) {
        int seg = i * 4 + w;
        gload16(W2t + (size_t)(seg * 16 + srow) * DD + 32 + sc * 8,
                SM + 16384 + 8192 + seg * 512);
    }
    // ---- epilogue 1: bn1+relu -> t into AT (same swizzle) ----
    #pragma unroll
    for (int m = 0; m < 2; ++m)
        #pragma unroll
        for (int n = 0; n < 8; ++n) {
            int cc = wn * 128 + n * 16 + lr;
            #pragma unroll
            for (int r = 0; r < 4; ++r) {
                int row = wm * 32 + m * 16 + rg * 4 + r;
                float y = acc[m][n][r] * sN[n] + svN[n];
                AT[row * 256 + ((((cc >> 3) ^ (row & 7)) << 3) | (cc & 7))] =
                    f2bf(y > 0.f ? y : 0.f);
            }
        }
    #pragma unroll
    for (int m = 0; m < 2; ++m)
        #pragma unroll
        for (int n = 0; n < 8; ++n) acc[m][n] = (f32x4)0.f;

    asm volatile("s_waitcnt lgkmcnt(0)" ::: "memory");
    __builtin_amdgcn_sched_barrier(0);
    __builtin_amdgcn_s_barrier();                // t visible; W2 stays in flight
    __builtin_amdgcn_sched_barrier(0);

    // ---- phase 2 K-loop (t from AT, W2 triple-buffered) ----
    #pragma unroll
    for (int kc = 0; kc < 8; ++kc) {
        if (kc < 7) asm volatile("s_waitcnt vmcnt(4)" ::: "memory");
        else        asm volatile("s_waitcnt vmcnt(0)" ::: "memory");
        __builtin_amdgcn_sched_barrier(0);
        __builtin_amdgcn_s_barrier();
        __builtin_amdgcn_sched_barrier(0);
        if (kc < 6) {
            int ko = (kc + 2) * 32;
            int bi = (kc + 2) % 3;
            #pragma unroll
            for (int i = 0; i < 4; ++i) {
                int seg = i * 4 + w;
                gload16(W2t + (size_t)(seg * 16 + srow) * DD + ko + sc * 8,
                        SM + 16384 + bi * 8192 + seg * 512);
            }
        }
        const ushort* Wb = SM + 16384 + (kc % 3) * 8192;
        bf16x8 ah[2], bh[8];
        #pragma unroll
        for (int mi = 0; mi < 2; ++mi) {
            int row = wm * 32 + mi * 16 + lr;
            ah[mi] = *(const bf16x8*)&AT[row * 256 + (((kc * 4 + kg) ^ (row & 7)) * 8)];
        }
        #pragma unroll
        for (int n = 0; n < 8; ++n)
            bh[n] = *(const bf16x8*)&Wb[(wn * 128 + n * 16 + lr) * 32 + kgp * 8];
        #pragma unroll
        for (int mi = 0; mi < 2; ++mi)
            #pragma unroll
            for (int n = 0; n < 8; ++n)
                acc[mi][n] = __builtin_amdgcn_mfma_f32_16x16x32_bf16(
                    ah[mi], bh[n], acc[mi][n], 0, 0, 0);
    }
    __builtin_amdgcn_s_barrier();                // all t reads done
    __builtin_amdgcn_sched_barrier(0);

    // ---- epilogue 2: bn2+relu -> h into AT (swizzled) -> coalesced stores ----
    {
        float sN2[8], svN2[8];
        #pragma unroll
        for (int n = 0; n < 8; ++n) {
            int jj = wn * 128 + n * 16 + lr;
            sN2[n]  = g2[jj] * rsqrtf(v2[jj] + EPSV);
            svN2[n] = (b2[jj] - m2[jj]) * sN2[n] + be2[jj];
        }
        #pragma unroll
        for (int m = 0; m < 2; ++m)
            #pragma unroll
            for (int n = 0; n < 8; ++n) {
                int cc = wn * 128 + n * 16 + lr;
                #pragma unroll
                for (int r = 0; r < 4; ++r) {
                    int row = wm * 32 + m * 16 + rg * 4 + r;
                    float y = acc[m][n][r] * sN2[n] + svN2[n];
                    AT[row * 256 + ((((cc >> 3) ^ (row & 7)) << 3) | (cc & 7))] =
                        f2bf(y > 0.f ? y : 0.f);
                }
            }
        asm volatile("s_waitcnt lgkmcnt(0)" ::: "memory");
        __builtin_amdgcn_sched_barrier(0);
        __builtin_amdgcn_s_barrier();            // h tile complete
        __builtin_amdgcn_sched_barrier(0);
        // coalesced readback: 2048 chunks, 8 per thread
        #pragma unroll
        for (int i = 0; i < 8; ++i) {
            int cid = tid + i * 256;
            int row = cid >> 5;
            int ci  = cid & 31;
            u16x8 vv = *(const u16x8*)&AT[row * 256 + ((ci ^ (row & 7)) * 8)];
            *(u16x8*)(O + (size_t)(m0 + row) * DD + ci * 8) = vv;
        }
    }

    // ---- fused score (+ sigmoid at last layer) for blocks owning rows 0-63 ----
    if ((m0 & (NN - 1)) == 0) {
        int b = m0 >> 11;
        for (int q = w; q < QQ; q += 4) {
            int chunk = lane >> 1;
            int phys  = chunk ^ (q & 7);
            ushort4 hv = *(const ushort4*)&AT[q * 256 + phys * 8 + (lane & 1) * 4];
            const float4 wv = *(const float4*)&pw[(l + 1) * DD + lane * 4];
            float s = bf2f(hv.x) * wv.x + bf2f(hv.y) * wv.y +
                      bf2f(hv.z) * wv.z + bf2f(hv.w) * wv.w;
            #pragma unroll
            for (int off = 32; off > 0; off >>= 1) s += __shfl_down(s, off);
            if (lane == 0) {
                float v = out[b * QQ + q] + s + pb[l + 1];
                out[b * QQ + q] = (l == LL - 1) ? 1.f / (1.f + expf(-v)) : v;
            }
        }
    }
}

// ---------- layer-0 score: batch-independent; ASSIGNS output ----------
__global__ __launch_bounds__(64) void k_score0(const float4* __restrict__ emo,
                                               const float4* __restrict__ pw,
                                               const float* __restrict__ pb,
                                               float* __restrict__ out)
{
    int q = blockIdx.x, t = threadIdx.x;
    float4 e = emo[q * 64 + t], wv = pw[t];
    float s = e.x * wv.x + e.y * wv.y + e.z * wv.z + e.w * wv.w;
    #pragma unroll
    for (int off = 32; off > 0; off >>= 1) s += __shfl_down(s, off);
    if (t == 0) {
        s += pb[0];
        for (int b = 0; b < BB; ++b) out[b * QQ + q] = s;
    }
}

extern "C" void kernel_launch(void* const* d_in, const int* in_sizes, int n_in,
                              void* d_out, int out_size, void* d_ws, size_t ws_size,
                              hipStream_t stream)
{
    const float* batch = (const float*)d_in[0];
    const int*   edges = (const int*)d_in[1];
    const float* emo   = (const float*)d_in[2];
    const float* w1    = (const float*)d_in[3];
    const float* b1    = (const float*)d_in[4];
    const float* m_g   = (const float*)d_in[5];
    const float* m_b   = (const float*)d_in[6];
    const float* m_m   = (const float*)d_in[7];
    const float* m_v   = (const float*)d_in[8];
    const float* w2    = (const float*)d_in[9];
    const float* b2    = (const float*)d_in[10];
    const float* g_g   = (const float*)d_in[11];
    const float* g_b   = (const float*)d_in[12];
    const float* g_m   = (const float*)d_in[13];
    const float* g_v   = (const float*)d_in[14];
    const float* pw    = (const float*)d_in[15];
    const float* pb    = (const float*)d_in[16];
    float* out = (float*)d_out;

    const size_t HSZ = (size_t)BB * NN * DD;
    const size_t WT  = (size_t)8 * DD * DD;

    ushort* h_hi = (ushort*)d_ws;
    ushort* P_hi = h_hi + HSZ;
    ushort* wt_hi = P_hi + HSZ;
    int* cnt     = (int*)(wt_hi + WT);
    int* row_ptr = cnt + NN;
    int* cursor  = row_ptr + (NN + 4);
    int* col     = cursor + NN;            // 16B-aligned

    const int* src = edges;
    const int* dst = edges + EE;

    (void)hipMemsetAsync(cnt, 0, NN * sizeof(int), stream);
    k_count<<<EE / 256, 256, 0, stream>>>(src, cnt);
    k_scan<<<1, 256, 0, stream>>>(cnt, row_ptr, cursor);
    k_fill<<<EE / 256, 256, 0, stream>>>(src, dst, cursor, col);
    k_wprep<<<512, 256, 0, stream>>>(w1, w2, wt_hi);
    k_prep0<<<4096, 256, 0, stream>>>((const float4*)batch, (const float4*)emo,
                                      (ushort4*)h_hi);
    k_score0<<<QQ, 64, 0, stream>>>((const float4*)emo, (const float4*)pw, pb, out);

    for (int l = 0; l < LL; ++l) {
        k_spmm6<<<8192, 256, 0, stream>>>(h_hi, row_ptr, col, P_hi);
        k_gemm_fused<<<1024, 256, 0, stream>>>(
            P_hi,
            wt_hi + (size_t)l * DD * DD, wt_hi + (size_t)(4 + l) * DD * DD,
            b1 + l * DD, m_g + l * DD, m_b + l * DD, m_m + l * DD, m_v + l * DD,
            b2 + l * DD, g_g + l * DD, g_b + l * DD, g_m + l * DD, g_v + l * DD,
            pw, pb, l,
            h_hi, out);
    }
}

// Round 21
// 307.443 us; speedup vs baseline: 1.0163x; 1.0163x over previous
//
#include <hip/hip_runtime.h>
#include <hip/hip_bf16.h>

#define NN 2048
#define QQ 9
#define DD 256
#define LL 4
#define BB 32
#define EE 32768
#define EPSV 1e-5f

typedef __attribute__((ext_vector_type(8))) short bf16x8;
typedef __attribute__((ext_vector_type(8))) ushort u16x8;
typedef __attribute__((ext_vector_type(4))) float f32x4;
typedef __attribute__((ext_vector_type(2))) float f32x2;
typedef __attribute__((ext_vector_type(4))) int i32x4;

__device__ __forceinline__ ushort f2bf(float x)
{
    uint u = __float_as_uint(x);
    u += 0x7FFFu + ((u >> 16) & 1u);
    return (ushort)(u >> 16);
}
__device__ __forceinline__ float bf2f(ushort h)
{
    return __uint_as_float(((uint)h) << 16);
}

// decode one u32 (2 packed bf16) and accumulate into a float2 (pk_add-friendly)
__device__ __forceinline__ void addw(uint wd, f32x2& a)
{
    f32x2 v;
    v.x = __uint_as_float(wd << 16);
    v.y = __uint_as_float(wd & 0xffff0000u);
    a += v;
}

// async global -> LDS, 16 bytes per lane; lptr wave-uniform (HW adds lane*16)
__device__ __forceinline__ void gload16(const ushort* g, ushort* l)
{
    __builtin_amdgcn_global_load_lds(
        (const __attribute__((address_space(1))) void*)g,
        (__attribute__((address_space(3))) void*)l, 16, 0, 0);
}

// ---------- CSR build ----------
__global__ void k_count(const int* __restrict__ src, int* __restrict__ cnt)
{
    int e = blockIdx.x * blockDim.x + threadIdx.x;
    if (e < EE) atomicAdd(&cnt[src[e]], 1);
}

__global__ __launch_bounds__(256) void k_scan(const int* __restrict__ cnt,
                                              int* __restrict__ row_ptr,
                                              int* __restrict__ cursor)
{
    __shared__ int part[256];
    int t = threadIdx.x;
    int local[8];
    int s = 0;
    #pragma unroll
    for (int i = 0; i < 8; ++i) { local[i] = cnt[t * 8 + i]; s += local[i]; }
    part[t] = s;
    __syncthreads();
    for (int off = 1; off < 256; off <<= 1) {
        int v = (t >= off) ? part[t - off] : 0;
        __syncthreads();
        part[t] += v;
        __syncthreads();
    }
    int run = part[t] - s;
    #pragma unroll
    for (int i = 0; i < 8; ++i) {
        int idx = t * 8 + i;
        row_ptr[idx] = run;
        cursor[idx]  = run;
        run += local[i];
    }
    if (t == 255) row_ptr[NN] = run;
}

__global__ void k_fill(const int* __restrict__ src, const int* __restrict__ dst,
                       int* __restrict__ cursor, int* __restrict__ col)
{
    int e = blockIdx.x * blockDim.x + threadIdx.x;
    if (e < EE) {
        int p = atomicAdd(&cursor[src[e]], 1);
        col[p] = dst[e];
    }
}

// ---------- h0 = bf16(batch with rows [0,Q) <- emotion_emb) ----------
__global__ void k_prep0(const float4* __restrict__ bf, const float4* __restrict__ emo,
                        ushort4* __restrict__ hhi)
{
    int total = BB * NN * (DD / 4);
    for (int idx = blockIdx.x * blockDim.x + threadIdx.x; idx < total;
         idx += gridDim.x * blockDim.x) {
        int d4 = idx & 63;
        int n  = (idx >> 6) & (NN - 1);
        float4 v = (n < QQ) ? emo[n * 64 + d4] : bf[idx];
        ushort4 h;
        h.x = f2bf(v.x); h.y = f2bf(v.y); h.z = f2bf(v.z); h.w = f2bf(v.w);
        hhi[idx] = h;
    }
}

// ---------- pooled = h + A.h : batch-paired gather, word-decode, unroll-16 ----------
// row stride in uint units = DD/2 = 128
__global__ __launch_bounds__(256) void k_spmm6(
    const ushort* __restrict__ phi,
    const int* __restrict__ row_ptr, const int* __restrict__ col,
    ushort* __restrict__ ohi)
{
    int x     = blockIdx.x & 7;          // XCD slice: batches [4x, 4x+4)
    int local = blockIdx.x >> 3;
    int w     = threadIdx.x >> 6;
    int t     = threadIdx.x & 63;
    int inst  = local * 4 + w;           // [0, 4096): (pair-of-batches, node)
    int pl    = inst >> 11;              // 0/1: which batch pair in this XCD
    int n     = inst & (NN - 1);
    int b     = x * 4 + pl * 2 + (t >> 5);   // lanes 0-31: batch b0; 32-63: b0+1
    int q     = t & 31;                  // 16B chunk: elems [8q, 8q+8)
    const uint* base = (const uint*)(phi + (size_t)b * NN * DD) + q * 4;

    f32x2 a[4];
    {
        uint4 sv = *(const uint4*)(base + (size_t)n * 128);
        a[0] = (f32x2)0.f; a[1] = (f32x2)0.f; a[2] = (f32x2)0.f; a[3] = (f32x2)0.f;
        addw(sv.x, a[0]); addw(sv.y, a[1]); addw(sv.z, a[2]); addw(sv.w, a[3]);
    }

    int beg = row_ptr[n], end = row_ptr[n + 1];
    int j = beg;
    for (; j < end && (j & 3); ++j) {
        uint4 g = *(const uint4*)(base + (size_t)col[j] * 128);
        addw(g.x, a[0]); addw(g.y, a[1]); addw(g.z, a[2]); addw(g.w, a[3]);
    }
    for (; j + 16 <= end; j += 16) {
        i32x4 c0 = *(const i32x4*)(col + j);
        i32x4 c1 = *(const i32x4*)(col + j + 4);
        i32x4 c2 = *(const i32x4*)(col + j + 8);
        i32x4 c3 = *(const i32x4*)(col + j + 12);
        uint4 g[16];
        g[0]  = *(const uint4*)(base + (size_t)c0.x * 128);
        g[1]  = *(const uint4*)(base + (size_t)c0.y * 128);
        g[2]  = *(const uint4*)(base + (size_t)c0.z * 128);
        g[3]  = *(const uint4*)(base + (size_t)c0.w * 128);
        g[4]  = *(const uint4*)(base + (size_t)c1.x * 128);
        g[5]  = *(const uint4*)(base + (size_t)c1.y * 128);
        g[6]  = *(const uint4*)(base + (size_t)c1.z * 128);
        g[7]  = *(const uint4*)(base + (size_t)c1.w * 128);
        g[8]  = *(const uint4*)(base + (size_t)c2.x * 128);
        g[9]  = *(const uint4*)(base + (size_t)c2.y * 128);
        g[10] = *(const uint4*)(base + (size_t)c2.z * 128);
        g[11] = *(const uint4*)(base + (size_t)c2.w * 128);
        g[12] = *(const uint4*)(base + (size_t)c3.x * 128);
        g[13] = *(const uint4*)(base + (size_t)c3.y * 128);
        g[14] = *(const uint4*)(base + (size_t)c3.z * 128);
        g[15] = *(const uint4*)(base + (size_t)c3.w * 128);
        #pragma unroll
        for (int u = 0; u < 16; ++u) {
            addw(g[u].x, a[0]); addw(g[u].y, a[1]);
            addw(g[u].z, a[2]); addw(g[u].w, a[3]);
        }
    }
    if (j + 8 <= end) {
        i32x4 c0 = *(const i32x4*)(col + j);
        i32x4 c1 = *(const i32x4*)(col + j + 4);
        uint4 g[8];
        g[0] = *(const uint4*)(base + (size_t)c0.x * 128);
        g[1] = *(const uint4*)(base + (size_t)c0.y * 128);
        g[2] = *(const uint4*)(base + (size_t)c0.z * 128);
        g[3] = *(const uint4*)(base + (size_t)c0.w * 128);
        g[4] = *(const uint4*)(base + (size_t)c1.x * 128);
        g[5] = *(const uint4*)(base + (size_t)c1.y * 128);
        g[6] = *(const uint4*)(base + (size_t)c1.z * 128);
        g[7] = *(const uint4*)(base + (size_t)c1.w * 128);
        #pragma unroll
        for (int u = 0; u < 8; ++u) {
            addw(g[u].x, a[0]); addw(g[u].y, a[1]);
            addw(g[u].z, a[2]); addw(g[u].w, a[3]);
        }
        j += 8;
    }
    if (j + 4 <= end) {
        i32x4 c = *(const i32x4*)(col + j);
        uint4 g[4];
        g[0] = *(const uint4*)(base + (size_t)c.x * 128);
        g[1] = *(const uint4*)(base + (size_t)c.y * 128);
        g[2] = *(const uint4*)(base + (size_t)c.z * 128);
        g[3] = *(const uint4*)(base + (size_t)c.w * 128);
        #pragma unroll
        for (int u = 0; u < 4; ++u) {
            addw(g[u].x, a[0]); addw(g[u].y, a[1]);
            addw(g[u].z, a[2]); addw(g[u].w, a[3]);
        }
        j += 4;
    }
    for (; j < end; ++j) {
        uint4 g = *(const uint4*)(base + (size_t)col[j] * 128);
        addw(g.x, a[0]); addw(g.y, a[1]); addw(g.z, a[2]); addw(g.w, a[3]);
    }

    u16x8 o;
    #pragma unroll
    for (int k = 0; k < 4; ++k) {
        o[2 * k]     = f2bf(a[k].x);
        o[2 * k + 1] = f2bf(a[k].y);
    }
    *(u16x8*)(ohi + ((size_t)b * NN + n) * DD + q * 8) = o;
}

// ---------- weight prep: Wt[mat][n][k] = bf16(W[mat][k][n]) ----------
__global__ __launch_bounds__(256) void k_wprep(const float* __restrict__ w1,
                                               const float* __restrict__ w2,
                                               ushort* __restrict__ wt_hi)
{
    __shared__ float tile[32][36];
    int bx = blockIdx.x;
    int mat = bx >> 6;
    int tt  = bx & 63;
    int tk = (tt >> 3) * 32;
    int tn = (tt & 7) * 32;
    const float* src = (mat < 4) ? (w1 + (size_t)mat * DD * DD)
                                 : (w2 + (size_t)(mat - 4) * DD * DD);
    int t = threadIdx.x;
    int r = t >> 3, c0 = (t & 7) * 4;
    float4 v = *(const float4*)(src + (size_t)(tk + r) * DD + tn + c0);
    tile[r][c0 + 0] = v.x; tile[r][c0 + 1] = v.y;
    tile[r][c0 + 2] = v.z; tile[r][c0 + 3] = v.w;
    __syncthreads();
    int nn = t >> 3, kq = (t & 7) * 4;
    ushort4 hh;
    hh.x = f2bf(tile[kq + 0][nn]); hh.y = f2bf(tile[kq + 1][nn]);
    hh.z = f2bf(tile[kq + 2][nn]); hh.w = f2bf(tile[kq + 3][nn]);
    size_t off = (size_t)mat * DD * DD + (size_t)(tn + nn) * DD + tk + kq;
    *(ushort4*)(wt_hi + off) = hh;
}

// ---------- fused layer GEMM + score: h = relu(bn2( relu(bn1(P@W1)) @ W2 )) ----------
// R13-proven: 64 rows x 256 N per block, 4 waves (32m x 128n). Double-buffered
// LDS tiles via global_load_lds with both-sides chunk-XOR swizzle.
__global__ __launch_bounds__(256) void k_gemm_fused(
    const ushort* __restrict__ A, const ushort* __restrict__ W1t,
    const ushort* __restrict__ W2t,
    const float* __restrict__ b1, const float* __restrict__ g1,
    const float* __restrict__ be1, const float* __restrict__ m1,
    const float* __restrict__ v1,
    const float* __restrict__ b2, const float* __restrict__ g2,
    const float* __restrict__ be2, const float* __restrict__ m2,
    const float* __restrict__ v2,
    const float* __restrict__ pw, const float* __restrict__ pb, int l,
    ushort* __restrict__ O, float* __restrict__ out)
{
    __shared__ alignas(16) ushort As[2][64 * 32];    //  8,192 B
    __shared__ alignas(16) ushort Ws[2][256 * 32];   // 32,768 B
    __shared__ alignas(16) ushort Ts[64][264];       // 33,792 B

    int tid = threadIdx.x;
    int x  = blockIdx.x & 7;                 // XCD-aligned with spmm partition
    int lm = blockIdx.x >> 3;
    int m0 = x * 8192 + lm * 64;
    int lane = tid & 63;
    int w = tid >> 6;                        // 4 waves
    int wm = w & 1, wn = w >> 1;             // wave tile: 32m x 128n
    int lr = lane & 15, kg = lane >> 4;
    int rg = lane >> 4;
    int kgp = kg ^ ((lr >> 1) & 3);          // swizzled read chunk

    // staging geometry (per lane): logical chunk fetched into physical slot
    int sc   = (lane & 3) ^ ((lane >> 3) & 3);   // source chunk (swizzle)
    int srow = lane >> 2;                        // row within 16-row segment
    const ushort* Aglob = A + (size_t)(m0 + w * 16 + srow) * DD + sc * 8;

    f32x4 acc[2][8];
    #pragma unroll
    for (int m = 0; m < 2; ++m)
        #pragma unroll
        for (int n = 0; n < 8; ++n) acc[m][n] = (f32x4)0.f;

    // ---- phase 1: t = relu(bn1(A @ W1)) ----
    {
        gload16(Aglob, &As[0][w * 512]);
        #pragma unroll
        for (int i = 0; i < 4; ++i) {
            int seg = i * 4 + w;
            gload16(W1t + (size_t)(seg * 16 + srow) * DD + sc * 8, &Ws[0][seg * 512]);
        }
    }
    int cur = 0;
    for (int kc = 0; kc < 8; ++kc) {
        __syncthreads();                     // drains DMA -> buf[cur] ready
        if (kc < 7) {
            int ko = (kc + 1) * 32;
            gload16(Aglob + ko, &As[cur ^ 1][w * 512]);
            #pragma unroll
            for (int i = 0; i < 4; ++i) {
                int seg = i * 4 + w;
                gload16(W1t + (size_t)(seg * 16 + srow) * DD + ko + sc * 8,
                        &Ws[cur ^ 1][seg * 512]);
            }
        }
        bf16x8 ah[2], bh[8];
        #pragma unroll
        for (int mi = 0; mi < 2; ++mi)
            ah[mi] = *(const bf16x8*)&As[cur][(wm * 32 + mi * 16 + lr) * 32 + kgp * 8];
        #pragma unroll
        for (int n = 0; n < 8; ++n)
            bh[n] = *(const bf16x8*)&Ws[cur][(wn * 128 + n * 16 + lr) * 32 + kgp * 8];
        #pragma unroll
        for (int mi = 0; mi < 2; ++mi)
            #pragma unroll
            for (int n = 0; n < 8; ++n)
                acc[mi][n] = __builtin_amdgcn_mfma_f32_16x16x32_bf16(
                    ah[mi], bh[n], acc[mi][n], 0, 0, 0);
        cur ^= 1;
    }
    // epilogue 1: bn1+relu -> Ts (bf16)
    {
        float sN[8], svN[8];
        #pragma unroll
        for (int n = 0; n < 8; ++n) {
            int jj = wn * 128 + n * 16 + lr;
            sN[n]  = g1[jj] * rsqrtf(v1[jj] + EPSV);
            svN[n] = (b1[jj] - m1[jj]) * sN[n] + be1[jj];
        }
        #pragma unroll
        for (int m = 0; m < 2; ++m)
            #pragma unroll
            for (int n = 0; n < 8; ++n) {
                int cc = wn * 128 + n * 16 + lr;
                #pragma unroll
                for (int r = 0; r < 4; ++r) {
                    float y = acc[m][n][r] * sN[n] + svN[n];
                    Ts[wm * 32 + m * 16 + rg * 4 + r][cc] = f2bf(y > 0.f ? y : 0.f);
                }
            }
    }
    #pragma unroll
    for (int m = 0; m < 2; ++m)
        #pragma unroll
        for (int n = 0; n < 8; ++n) acc[m][n] = (f32x4)0.f;

    // ---- phase 2: h = relu(bn2(t @ W2)), t from Ts, W2 staged via DMA ----
    {
        #pragma unroll
        for (int i = 0; i < 4; ++i) {
            int seg = i * 4 + w;
            gload16(W2t + (size_t)(seg * 16 + srow) * DD + sc * 8, &Ws[0][seg * 512]);
        }
    }
    cur = 0;
    for (int kc = 0; kc < 8; ++kc) {
        __syncthreads();                     // Ts + buf[cur] ready
        if (kc < 7) {
            int ko = (kc + 1) * 32;
            #pragma unroll
            for (int i = 0; i < 4; ++i) {
                int seg = i * 4 + w;
                gload16(W2t + (size_t)(seg * 16 + srow) * DD + ko + sc * 8,
                        &Ws[cur ^ 1][seg * 512]);
            }
        }
        bf16x8 a2[2], bh[8];
        #pragma unroll
        for (int mi = 0; mi < 2; ++mi)
            a2[mi] = *(const bf16x8*)&Ts[wm * 32 + mi * 16 + lr][kc * 32 + kg * 8];
        #pragma unroll
        for (int n = 0; n < 8; ++n)
            bh[n] = *(const bf16x8*)&Ws[cur][(wn * 128 + n * 16 + lr) * 32 + kgp * 8];
        #pragma unroll
        for (int mi = 0; mi < 2; ++mi)
            #pragma unroll
            for (int n = 0; n < 8; ++n)
                acc[mi][n] = __builtin_amdgcn_mfma_f32_16x16x32_bf16(
                    a2[mi], bh[n], acc[mi][n], 0, 0, 0);
        cur ^= 1;
    }
    __syncthreads();                         // all Ts reads done before overwrite

    // epilogue 2: bn2+relu -> Ts (repack scratch) -> coalesced 16B stores
    {
        float sN[8], svN[8];
        #pragma unroll
        for (int n = 0; n < 8; ++n) {
            int jj = wn * 128 + n * 16 + lr;
            sN[n]  = g2[jj] * rsqrtf(v2[jj] + EPSV);
            svN[n] = (b2[jj] - m2[jj]) * sN[n] + be2[jj];
        }
        #pragma unroll
        for (int m = 0; m < 2; ++m)
            #pragma unroll
            for (int n = 0; n < 8; ++n) {
                int cc = wn * 128 + n * 16 + lr;
                #pragma unroll
                for (int r = 0; r < 4; ++r) {
                    float y = acc[m][n][r] * sN[n] + svN[n];
                    Ts[wm * 32 + m * 16 + rg * 4 + r][cc] = f2bf(y > 0.f ? y : 0.f);
                }
            }
        // wave-private readback (in-order DS + compiler waitcnt give visibility)
        #pragma unroll
        for (int i = 0; i < 8; ++i) {
            int cid = lane + i * 64;         // 512 chunks: 32 rows x 16 chunks
            int row = cid >> 4, c8 = cid & 15;
            u16x8 vv = *(const u16x8*)&Ts[wm * 32 + row][wn * 128 + c8 * 8];
            *(u16x8*)(O + (size_t)(m0 + wm * 32 + row) * DD + wn * 128 + c8 * 8) = vv;
        }
    }

    // ---- fused score (+ sigmoid at last layer) for the block owning rows 0-63 ----
    __syncthreads();                         // all waves' Ts h-values visible
    if ((m0 & (NN - 1)) == 0) {
        int b = m0 >> 11;
        for (int q = w; q < QQ; q += 4) {
            ushort4 hv = *(const ushort4*)&Ts[q][lane * 4];
            const float4 wv = *(const float4*)&pw[(l + 1) * DD + lane * 4];
            float s = bf2f(hv.x) * wv.x + bf2f(hv.y) * wv.y +
                      bf2f(hv.z) * wv.z + bf2f(hv.w) * wv.w;
            #pragma unroll
            for (int off = 32; off > 0; off >>= 1) s += __shfl_down(s, off);
            if (lane == 0) {
                float v = out[b * QQ + q] + s + pb[l + 1];
                out[b * QQ + q] = (l == LL - 1) ? 1.f / (1.f + expf(-v)) : v;
            }
        }
    }
}

// ---------- layer-0 score: batch-independent; ASSIGNS output ----------
__global__ __launch_bounds__(64) void k_score0(const float4* __restrict__ emo,
                                               const float4* __restrict__ pw,
                                               const float* __restrict__ pb,
                                               float* __restrict__ out)
{
    int q = blockIdx.x, t = threadIdx.x;
    float4 e = emo[q * 64 + t], wv = pw[t];
    float s = e.x * wv.x + e.y * wv.y + e.z * wv.z + e.w * wv.w;
    #pragma unroll
    for (int off = 32; off > 0; off >>= 1) s += __shfl_down(s, off);
    if (t == 0) {
        s += pb[0];
        for (int b = 0; b < BB; ++b) out[b * QQ + q] = s;
    }
}

extern "C" void kernel_launch(void* const* d_in, const int* in_sizes, int n_in,
                              void* d_out, int out_size, void* d_ws, size_t ws_size,
                              hipStream_t stream)
{
    const float* batch = (const float*)d_in[0];
    const int*   edges = (const int*)d_in[1];
    const float* emo   = (const float*)d_in[2];
    const float* w1    = (const float*)d_in[3];
    const float* b1    = (const float*)d_in[4];
    const float* m_g   = (const float*)d_in[5];
    const float* m_b   = (const float*)d_in[6];
    const float* m_m   = (const float*)d_in[7];
    const float* m_v   = (const float*)d_in[8];
    const float* w2    = (const float*)d_in[9];
    const float* b2    = (const float*)d_in[10];
    const float* g_g   = (const float*)d_in[11];
    const float* g_b   = (const float*)d_in[12];
    const float* g_m   = (const float*)d_in[13];
    const float* g_v   = (const float*)d_in[14];
    const float* pw    = (const float*)d_in[15];
    const float* pb    = (const float*)d_in[16];
    float* out = (float*)d_out;

    const size_t HSZ = (size_t)BB * NN * DD;
    const size_t WT  = (size_t)8 * DD * DD;

    ushort* h_hi = (ushort*)d_ws;
    ushort* P_hi = h_hi + HSZ;
    ushort* wt_hi = P_hi + HSZ;
    int* cnt     = (int*)(wt_hi + WT);
    int* row_ptr = cnt + NN;
    int* cursor  = row_ptr + (NN + 4);
    int* col     = cursor + NN;            // 16B-aligned

    const int* src = edges;
    const int* dst = edges + EE;

    (void)hipMemsetAsync(cnt, 0, NN * sizeof(int), stream);
    k_count<<<EE / 256, 256, 0, stream>>>(src, cnt);
    k_scan<<<1, 256, 0, stream>>>(cnt, row_ptr, cursor);
    k_fill<<<EE / 256, 256, 0, stream>>>(src, dst, cursor, col);
    k_wprep<<<512, 256, 0, stream>>>(w1, w2, wt_hi);
    k_prep0<<<4096, 256, 0, stream>>>((const float4*)batch, (const float4*)emo,
                                      (ushort4*)h_hi);
    k_score0<<<QQ, 64, 0, stream>>>((const float4*)emo, (const float4*)pw, pb, out);

    for (int l = 0; l < LL; ++l) {
        k_spmm6<<<8192, 256, 0, stream>>>(h_hi, row_ptr, col, P_hi);
        k_gemm_fused<<<1024, 256, 0, stream>>>(
            P_hi,
            wt_hi + (size_t)l * DD * DD, wt_hi + (size_t)(4 + l) * DD * DD,
            b1 + l * DD, m_g + l * DD, m_b + l * DD, m_m + l * DD, m_v + l * DD,
            b2 + l * DD, g_g + l * DD, g_b + l * DD, g_m + l * DD, g_v + l * DD,
            pw, pb, l,
            h_hi, out);
    }
}